// Round 8
// baseline (7662.186 us; speedup 1.0000x reference)
//
#include <hip/hip_runtime.h>

// ---------------------------------------------------------------------------
// LSTM scan, B=64 L=512 D=1024. Round 8 = R4 structure (best passing) with
// sync-cost cuts:
//   - tree arrive per group: 8 leaves x 8 + root 8, ACQ_REL (release side)
//   - 8 REPLICATED step flags per group (spread 64 pollers over 8 lines)
//   - nontemporal h/out stores (land at LLC -> release writeback near-free)
//   - out store moved into barrier shadow (off inter-WG critical path)
//   - x@Wk MFMAs for t+1 in the shadow (they double as xh prefetch; R7 proved
//     per-step cold scalar reads through the invalidated caches cost more)
// Protocol (R4-proven): stores -> syncthreads(vmcnt0) -> ACQ_REL RMW chain ->
// RELEASE flag stores -> relaxed poll -> ONE agent acquire fence -> loads.
// ---------------------------------------------------------------------------

typedef float    f32x4 __attribute__((ext_vector_type(4)));
typedef _Float16 half8 __attribute__((ext_vector_type(8)));
typedef _Float16 half4 __attribute__((ext_vector_type(4)));

#define B_  64
#define L_  512
#define D_  1024
#define N3_ 3072

// ws layout (bytes)
#define WKT_OFF 0LL          // f16 [3072][1024]   6291456
#define WRT_OFF 6291456LL    // f16 [3072][1024]   6291456
#define XH_OFF  12582912LL   // f16 [B*L][1024]   67108864
#define H16_OFF 79691776LL   // f16 [2][64][1024]   262144
#define BAR_OFF 79953920LL   // unsigned[4096]       16384

__device__ __forceinline__ float sigmoidf_fast(float x) {
  return __builtin_amdgcn_rcpf(1.f + __builtin_amdgcn_exp2f(-1.4426950408889634f * x));
}
__device__ __forceinline__ float tanhf_fast(float x) {
  return 1.f - 2.f * __builtin_amdgcn_rcpf(1.f + __builtin_amdgcn_exp2f(2.8853900817779268f * x));
}

// pinned (non-rematerializable) cached 16B load
#define ALOAD(dst, addr) \
  asm volatile("global_load_dwordx4 %0, %1, off" : "=v"(dst) : "v"(addr))
#define VMCNT0() asm volatile("s_waitcnt vmcnt(0)" ::: "memory")

// ---------------- prep: transpose + f32->f16 (Wk and Wr) -------------------
__global__ __launch_bounds__(256) void transpose_f16(
    const float* __restrict__ Wk, const float* __restrict__ Wr,
    _Float16* __restrict__ WkT, _Float16* __restrict__ WrT)
{
  __shared__ float tile[32][33];
  int b = blockIdx.x;
  const float* in = Wk; _Float16* outp = WkT;
  if (b >= 3072) { b -= 3072; in = Wr; outp = WrT; }
  const int n0 = (b % 96) * 32;
  const int k0 = (b / 96) * 32;
  const int tx = threadIdx.x & 31, ty = threadIdx.x >> 5;
#pragma unroll
  for (int i = 0; i < 32; i += 8)
    tile[ty + i][tx] = in[(size_t)(k0 + ty + i) * N3_ + n0 + tx];
  __syncthreads();
#pragma unroll
  for (int i = 0; i < 32; i += 8)
    outp[(size_t)(n0 + ty + i) * D_ + k0 + tx] = (_Float16)tile[tx][ty + i];
}

// ---------------- prep: x -> f16, h0 -> BOTH h16 buffers -------------------
__global__ void convert_inputs(const f32x4* __restrict__ x, const f32x4* __restrict__ h0,
                               half4* __restrict__ xh, half4* __restrict__ h16a,
                               half4* __restrict__ h16b)
{
  const int NX = (B_ * L_ * D_) / 4;
  const int NH = (B_ * D_) / 4;
  for (int i = blockIdx.x * blockDim.x + threadIdx.x; i < NX + NH;
       i += gridDim.x * blockDim.x) {
    if (i < NX) {
      xh[i] = __builtin_convertvector(x[i], half4);
    } else {
      half4 v = __builtin_convertvector(h0[i - NX], half4);
      h16a[i - NX] = v;
      h16b[i - NX] = v;
    }
  }
}

// ---------------- persistent scan ------------------------------------------
// 256 WGs = 4 groups (b-tiles) x 64 d-slices; 4 waves own K-slices of 256.
// Barrier space per group (u32 indices, group stride 1024):
//   leaves:   base + leaf*16     (8 leaves, 64B apart, 8 WGs each)
//   root:     base + 256
//   flags:    base + 512 + leaf*16   (8 replicas, 64B apart)
__global__ __launch_bounds__(256, 1) void lstm_scan(
    const _Float16* __restrict__ WkT,   // [3072][1024]
    const _Float16* __restrict__ WrT,   // [3072][1024]
    const _Float16* __restrict__ xh,    // [B*L][1024]
    const float*    __restrict__ c0,    // [64][1024]
    float*          __restrict__ out,   // [64][512][1024]
    _Float16*       __restrict__ h16,   // [2][64][1024]
    unsigned*       __restrict__ bar)
{
  const int tid = threadIdx.x, wave = tid >> 6, lane = tid & 63;
  const int bid = blockIdx.x;
  const int grp = bid & 3;           // b-tile group (independent scan)
  const int ord = bid >> 2;          // d-slice 0..63
  const int leaf = ord >> 3;         // 0..7
  const int b0 = grp * 16;
  const int d0 = ord * 16;
  const int l15 = lane & 15, l4h = lane >> 4;
  const int kbase = wave * 256;

  unsigned* const base  = bar + grp * 1024;
  unsigned* const leafp = base + leaf * 16;
  unsigned* const rootp = base + 256;
  unsigned* const flagp = base + 512 + leaf * 16;

  // ---- stationary weight fragments (asm loads; live in VGPR/AGPR file) ----
  half8 Wkf[3][8], Wrf[3][8];
#pragma unroll
  for (int g = 0; g < 3; ++g) {
    const _Float16* rr = WrT + (size_t)(g * D_ + d0 + l15) * D_ + kbase + l4h * 8;
    const _Float16* kr = WkT + (size_t)(g * D_ + d0 + l15) * D_ + kbase + l4h * 8;
#pragma unroll
    for (int kt = 0; kt < 8; ++kt) {
      ALOAD(Wrf[g][kt], rr + kt * 32);
      ALOAD(Wkf[g][kt], kr + kt * 32);
    }
  }
  VMCNT0();

  const int rb = tid >> 4;   // batch within tile
  const int rd = tid & 15;   // d within tile
  float c = c0[(size_t)(b0 + rb) * D_ + d0 + rd];

  __shared__ float part[4][48][20];

  const _Float16* xrow = xh + ((size_t)(b0 + l15) * L_) * D_ + kbase + l4h * 8;
  const size_t hoff   = (size_t)(b0 + l15) * D_ + kbase + l4h * 8;
  const size_t outidx = ((size_t)(b0 + rb) * L_) * D_ + d0 + rd;
  const size_t hidx   = (size_t)(b0 + rb) * D_ + d0 + rd;

  _Float16* hc = h16;            // h_t (both buffers pre-initialized with h0)
  _Float16* hn = h16 + B_ * D_;  // h_{t+1}

  f32x4 acc[3], acc2[3];
#pragma unroll
  for (int g = 0; g < 3; ++g) { f32x4 z = {0.f,0.f,0.f,0.f}; acc[g] = z; acc2[g] = z; }
  // prologue: x-part for t=0
#pragma unroll
  for (int kt = 0; kt < 8; ++kt) {
    half8 afx = *(const half8*)(xrow + kt * 32);
#pragma unroll
    for (int g = 0; g < 3; ++g)
      acc[g] = __builtin_amdgcn_mfma_f32_16x16x32_f16(afx, Wkf[g][kt], acc[g], 0, 0, 0);
  }

  for (int t = 0; t < L_; ++t) {
    // ---- h fragments (plain loads; fresh due to last step's acquire) ----
    half8 af[8];
    const _Float16* hrow = hc + hoff;
#pragma unroll
    for (int kt = 0; kt < 8; ++kt) af[kt] = *(const half8*)(hrow + kt * 32);

#pragma unroll
    for (int kt = 0; kt < 8; ++kt)
#pragma unroll
      for (int g = 0; g < 3; ++g)
        acc[g] = __builtin_amdgcn_mfma_f32_16x16x32_f16(af[kt], Wrf[g][kt], acc[g], 0, 0, 0);

    // ---- cross-wave reduce via LDS ----
#pragma unroll
    for (int g = 0; g < 3; ++g)
      *(f32x4*)&part[wave][g * 16 + l15][l4h * 4] = acc[g];
    __syncthreads();

    float fv = 0.f, ov = 0.f, gv = 0.f;
#pragma unroll
    for (int w = 0; w < 4; ++w) {
      fv += part[w][rd][rb];
      ov += part[w][16 + rd][rb];
      gv += part[w][32 + rd][rb];
    }
    const float sf = sigmoidf_fast(fv);
    const float tg = tanhf_fast(gv);
    c = c * sf + (1.f - sf) * tg;
    const float h = sigmoidf_fast(ov) * tanhf_fast(c);

    // h store must precede arrive; NT -> lands at LLC, nothing dirty in L2
    __builtin_nontemporal_store((_Float16)h, hn + hidx);

    // ---- tree arrive: ACQ_REL RMWs are the release (R4-proven) ----
    __syncthreads();   // implicit vmcnt(0): h stores retired
    if (tid == 0) {
      unsigned a = __hip_atomic_fetch_add(leafp, 1u, __ATOMIC_ACQ_REL,
                                          __HIP_MEMORY_SCOPE_AGENT);
      if (a == (unsigned)(8 * (t + 1) - 1)) {          // leaf closer
        unsigned r = __hip_atomic_fetch_add(rootp, 1u, __ATOMIC_ACQ_REL,
                                            __HIP_MEMORY_SCOPE_AGENT);
        if (r == (unsigned)(8 * (t + 1) - 1)) {        // root closer
#pragma unroll
          for (int i = 0; i < 8; ++i)
            __hip_atomic_store(base + 512 + i * 16, (unsigned)(t + 1),
                               __ATOMIC_RELEASE, __HIP_MEMORY_SCOPE_AGENT);
        }
      }
    }

    // ---- barrier shadow: out store + x-part MFMAs for t+1 ----
    __builtin_nontemporal_store(h, out + outidx + (size_t)t * D_);
    if (t + 1 < L_) {
#pragma unroll
      for (int g = 0; g < 3; ++g) { f32x4 z = {0.f,0.f,0.f,0.f}; acc2[g] = z; }
      const _Float16* xr = xrow + (size_t)(t + 1) * D_;
#pragma unroll
      for (int kt = 0; kt < 8; ++kt) {
        half8 afx = *(const half8*)(xr + kt * 32);
#pragma unroll
        for (int g = 0; g < 3; ++g)
          acc2[g] = __builtin_amdgcn_mfma_f32_16x16x32_f16(afx, Wkf[g][kt], acc2[g], 0, 0, 0);
      }
    }
    __builtin_amdgcn_sched_barrier(0);   // keep shadow work before the wait

    // ---- wait: relaxed poll on own replica + ONE agent acquire fence ----
    if (tid == 0) {
      while (__hip_atomic_load(flagp, __ATOMIC_RELAXED, __HIP_MEMORY_SCOPE_AGENT)
             < (unsigned)(t + 1)) {
        __builtin_amdgcn_s_sleep(1);
      }
      __builtin_amdgcn_fence(__ATOMIC_ACQUIRE, "agent");  // inv L1+L2 once
    }
    __syncthreads();

#pragma unroll
    for (int g = 0; g < 3; ++g) acc[g] = acc2[g];
    _Float16* tmp = hc; hc = hn; hn = tmp;
  }
}

// ---------------------------------------------------------------------------
extern "C" void kernel_launch(void* const* d_in, const int* in_sizes, int n_in,
                              void* d_out, int out_size, void* d_ws, size_t ws_size,
                              hipStream_t stream) {
  const float* x  = (const float*)d_in[0];
  const float* Wk = (const float*)d_in[1];
  const float* Wr = (const float*)d_in[2];
  const float* c0 = (const float*)d_in[3];
  const float* h0 = (const float*)d_in[4];
  float* out = (float*)d_out;

  char* ws = (char*)d_ws;
  _Float16* WkT = (_Float16*)(ws + WKT_OFF);
  _Float16* WrT = (_Float16*)(ws + WRT_OFF);
  _Float16* xh  = (_Float16*)(ws + XH_OFF);
  _Float16* h16 = (_Float16*)(ws + H16_OFF);
  unsigned* bar = (unsigned*)(ws + BAR_OFF);

  hipMemsetAsync(bar, 0, 16384, stream);

  hipLaunchKernelGGL(transpose_f16, dim3(6144), dim3(256), 0, stream,
                     Wk, Wr, WkT, WrT);
  hipLaunchKernelGGL(convert_inputs, dim3(2048), dim3(256), 0, stream,
                     (const f32x4*)x, (const f32x4*)h0,
                     (half4*)xh, (half4*)h16, (half4*)(h16 + B_ * D_));

  void* kargs[7] = {(void*)&WkT, (void*)&WrT, (void*)&xh, (void*)&c0,
                    (void*)&out, (void*)&h16, (void*)&bar};
  hipLaunchCooperativeKernel((void*)lstm_scan, dim3(256), dim3(256), kargs, 0, stream);
}

// Round 9
// 5234.907 us; speedup vs baseline: 1.4637x; 1.4637x over previous
//
#include <hip/hip_runtime.h>

// ---------------------------------------------------------------------------
// LSTM scan, B=64 L=512 D=1024. Round 9 = R4 (best passing, 10.3us/step)
// minus two critical-path costs:
//   1. no flag: pollers spin on the arrival counter itself (release sequence
//      on one location + acquire fence == R4 semantics, one less LLC hop)
//   2. out staged in LDS, dumped every 16 steps in the barrier shadow with NT
//      stores -> per-step dirty L2 is just h16 (128KB chip-wide), so each
//      arrival's ACQ_REL writeback is cheap
// R8 lesson: flat 64-way RMW on one line beats tree (dependent release hops
// are the expensive part, not RMW fan-in).
// ---------------------------------------------------------------------------

typedef float    f32x4 __attribute__((ext_vector_type(4)));
typedef _Float16 half8 __attribute__((ext_vector_type(8)));
typedef _Float16 half4 __attribute__((ext_vector_type(4)));

#define B_  64
#define L_  512
#define D_  1024
#define N3_ 3072

// ws layout (bytes)
#define WKT_OFF 0LL          // f16 [3072][1024]   6291456
#define WRT_OFF 6291456LL    // f16 [3072][1024]   6291456
#define XH_OFF  12582912LL   // f16 [B*L][1024]   67108864
#define H16_OFF 79691776LL   // f16 [2][64][1024]   262144
#define BAR_OFF 79953920LL   // unsigned[1024]        4096

__device__ __forceinline__ float sigmoidf_fast(float x) {
  return __builtin_amdgcn_rcpf(1.f + __builtin_amdgcn_exp2f(-1.4426950408889634f * x));
}
__device__ __forceinline__ float tanhf_fast(float x) {
  return 1.f - 2.f * __builtin_amdgcn_rcpf(1.f + __builtin_amdgcn_exp2f(2.8853900817779268f * x));
}

// pinned (non-rematerializable) cached 16B load
#define ALOAD(dst, addr) \
  asm volatile("global_load_dwordx4 %0, %1, off" : "=v"(dst) : "v"(addr))
#define VMCNT0() asm volatile("s_waitcnt vmcnt(0)" ::: "memory")

// ---------------- prep: transpose + f32->f16 (Wk and Wr) -------------------
__global__ __launch_bounds__(256) void transpose_f16(
    const float* __restrict__ Wk, const float* __restrict__ Wr,
    _Float16* __restrict__ WkT, _Float16* __restrict__ WrT)
{
  __shared__ float tile[32][33];
  int b = blockIdx.x;
  const float* in = Wk; _Float16* outp = WkT;
  if (b >= 3072) { b -= 3072; in = Wr; outp = WrT; }
  const int n0 = (b % 96) * 32;
  const int k0 = (b / 96) * 32;
  const int tx = threadIdx.x & 31, ty = threadIdx.x >> 5;
#pragma unroll
  for (int i = 0; i < 32; i += 8)
    tile[ty + i][tx] = in[(size_t)(k0 + ty + i) * N3_ + n0 + tx];
  __syncthreads();
#pragma unroll
  for (int i = 0; i < 32; i += 8)
    outp[(size_t)(n0 + ty + i) * D_ + k0 + tx] = (_Float16)tile[tx][ty + i];
}

// ---------------- prep: x -> f16, h0 -> BOTH h16 buffers -------------------
__global__ void convert_inputs(const f32x4* __restrict__ x, const f32x4* __restrict__ h0,
                               half4* __restrict__ xh, half4* __restrict__ h16a,
                               half4* __restrict__ h16b)
{
  const int NX = (B_ * L_ * D_) / 4;
  const int NH = (B_ * D_) / 4;
  for (int i = blockIdx.x * blockDim.x + threadIdx.x; i < NX + NH;
       i += gridDim.x * blockDim.x) {
    if (i < NX) {
      xh[i] = __builtin_convertvector(x[i], half4);
    } else {
      half4 v = __builtin_convertvector(h0[i - NX], half4);
      h16a[i - NX] = v;
      h16b[i - NX] = v;
    }
  }
}

// ---------------- persistent scan ------------------------------------------
// 256 WGs = 4 groups (b-tiles) x 64 d-slices; 4 waves own K-slices of 256.
// Barrier: ONE monotone counter per group (bar + grp*64); poll it directly.
__global__ __launch_bounds__(256, 1) void lstm_scan(
    const _Float16* __restrict__ WkT,   // [3072][1024]
    const _Float16* __restrict__ WrT,   // [3072][1024]
    const _Float16* __restrict__ xh,    // [B*L][1024]
    const float*    __restrict__ c0,    // [64][1024]
    float*          __restrict__ out,   // [64][512][1024]
    _Float16*       __restrict__ h16,   // [2][64][1024]
    unsigned*       __restrict__ bar)
{
  const int tid = threadIdx.x, wave = tid >> 6, lane = tid & 63;
  const int bid = blockIdx.x;
  const int grp = bid & 3;           // b-tile group (independent scan)
  const int ord = bid >> 2;          // d-slice 0..63
  const int b0 = grp * 16;
  const int d0 = ord * 16;
  const int l15 = lane & 15, l4h = lane >> 4;
  const int kbase = wave * 256;

  unsigned* const cntp = bar + grp * 64;   // monotone arrival counter

  // ---- stationary weight fragments (asm loads; VGPR/AGPR resident) ----
  half8 Wkf[3][8], Wrf[3][8];
#pragma unroll
  for (int g = 0; g < 3; ++g) {
    const _Float16* rr = WrT + (size_t)(g * D_ + d0 + l15) * D_ + kbase + l4h * 8;
    const _Float16* kr = WkT + (size_t)(g * D_ + d0 + l15) * D_ + kbase + l4h * 8;
#pragma unroll
    for (int kt = 0; kt < 8; ++kt) {
      ALOAD(Wrf[g][kt], rr + kt * 32);
      ALOAD(Wkf[g][kt], kr + kt * 32);
    }
  }
  VMCNT0();

  const int rb = tid >> 4;   // batch within tile
  const int rd = tid & 15;   // d within tile
  float c = c0[(size_t)(b0 + rb) * D_ + d0 + rd];

  __shared__ float part[4][48][20];
  __shared__ float obuf[16][256];   // 16 steps of h per thread (off dirty set)

  const _Float16* xrow = xh + ((size_t)(b0 + l15) * L_) * D_ + kbase + l4h * 8;
  const size_t hoff   = (size_t)(b0 + l15) * D_ + kbase + l4h * 8;
  const size_t outidx = ((size_t)(b0 + rb) * L_) * D_ + d0 + rd;
  const size_t hidx   = (size_t)(b0 + rb) * D_ + d0 + rd;

  _Float16* hc = h16;            // h_t (both buffers pre-initialized with h0)
  _Float16* hn = h16 + B_ * D_;  // h_{t+1}

  f32x4 acc[3], acc2[3];
#pragma unroll
  for (int g = 0; g < 3; ++g) { f32x4 z = {0.f,0.f,0.f,0.f}; acc[g] = z; acc2[g] = z; }
  // prologue: x-part for t=0
#pragma unroll
  for (int kt = 0; kt < 8; ++kt) {
    half8 afx = *(const half8*)(xrow + kt * 32);
#pragma unroll
    for (int g = 0; g < 3; ++g)
      acc[g] = __builtin_amdgcn_mfma_f32_16x16x32_f16(afx, Wkf[g][kt], acc[g], 0, 0, 0);
  }

  for (int t = 0; t < L_; ++t) {
    // ---- h fragments (plain loads; fresh due to last step's acquire) ----
    half8 af[8];
    const _Float16* hrow = hc + hoff;
#pragma unroll
    for (int kt = 0; kt < 8; ++kt) af[kt] = *(const half8*)(hrow + kt * 32);

#pragma unroll
    for (int kt = 0; kt < 8; ++kt)
#pragma unroll
      for (int g = 0; g < 3; ++g)
        acc[g] = __builtin_amdgcn_mfma_f32_16x16x32_f16(af[kt], Wrf[g][kt], acc[g], 0, 0, 0);

    // ---- cross-wave reduce via LDS ----
#pragma unroll
    for (int g = 0; g < 3; ++g)
      *(f32x4*)&part[wave][g * 16 + l15][l4h * 4] = acc[g];
    __syncthreads();

    float fv = 0.f, ov = 0.f, gv = 0.f;
#pragma unroll
    for (int w = 0; w < 4; ++w) {
      fv += part[w][rd][rb];
      ov += part[w][16 + rd][rb];
      gv += part[w][32 + rd][rb];
    }
    const float sf = sigmoidf_fast(fv);
    const float tg = tanhf_fast(gv);
    c = c * sf + (1.f - sf) * tg;
    const float h = sigmoidf_fast(ov) * tanhf_fast(c);

    hn[hidx] = (_Float16)h;     // the ONLY per-step global dirty data
    obuf[t & 15][tid] = h;      // out goes to LDS, dumped every 16 steps

    // ---- arrive: flat ACQ_REL RMW on group counter (R4-proven) ----
    __syncthreads();   // implicit vmcnt(0): h store retired to L2
    if (tid == 0)
      __hip_atomic_fetch_add(cntp, 1u, __ATOMIC_ACQ_REL, __HIP_MEMORY_SCOPE_AGENT);

    // ---- barrier shadow: out dump (every 16 steps) + x-MFMAs for t+1 ----
    if ((t & 15) == 15) {
      float* op = out + outidx + (size_t)(t - 15) * D_;
#pragma unroll
      for (int j = 0; j < 16; ++j)
        __builtin_nontemporal_store(obuf[j][tid], op + (size_t)j * D_);
    }
    if (t + 1 < L_) {
#pragma unroll
      for (int g = 0; g < 3; ++g) { f32x4 z = {0.f,0.f,0.f,0.f}; acc2[g] = z; }
      const _Float16* xr = xrow + (size_t)(t + 1) * D_;
#pragma unroll
      for (int kt = 0; kt < 8; ++kt) {
        half8 afx = *(const half8*)(xr + kt * 32);
#pragma unroll
        for (int g = 0; g < 3; ++g)
          acc2[g] = __builtin_amdgcn_mfma_f32_16x16x32_f16(afx, Wkf[g][kt], acc2[g], 0, 0, 0);
      }
    }
    __builtin_amdgcn_sched_barrier(0);   // keep shadow work before the wait

    // ---- wait: relaxed poll of the counter + ONE agent acquire fence ----
    if (tid == 0) {
      while (__hip_atomic_load(cntp, __ATOMIC_RELAXED, __HIP_MEMORY_SCOPE_AGENT)
             < (unsigned)(64 * (t + 1))) {
        __builtin_amdgcn_s_sleep(1);
      }
      __builtin_amdgcn_fence(__ATOMIC_ACQUIRE, "agent");
    }
    __syncthreads();

#pragma unroll
    for (int g = 0; g < 3; ++g) acc[g] = acc2[g];
    _Float16* tmp = hc; hc = hn; hn = tmp;
  }
}

// ---------------------------------------------------------------------------
extern "C" void kernel_launch(void* const* d_in, const int* in_sizes, int n_in,
                              void* d_out, int out_size, void* d_ws, size_t ws_size,
                              hipStream_t stream) {
  const float* x  = (const float*)d_in[0];
  const float* Wk = (const float*)d_in[1];
  const float* Wr = (const float*)d_in[2];
  const float* c0 = (const float*)d_in[3];
  const float* h0 = (const float*)d_in[4];
  float* out = (float*)d_out;

  char* ws = (char*)d_ws;
  _Float16* WkT = (_Float16*)(ws + WKT_OFF);
  _Float16* WrT = (_Float16*)(ws + WRT_OFF);
  _Float16* xh  = (_Float16*)(ws + XH_OFF);
  _Float16* h16 = (_Float16*)(ws + H16_OFF);
  unsigned* bar = (unsigned*)(ws + BAR_OFF);

  hipMemsetAsync(bar, 0, 4096, stream);

  hipLaunchKernelGGL(transpose_f16, dim3(6144), dim3(256), 0, stream,
                     Wk, Wr, WkT, WrT);
  hipLaunchKernelGGL(convert_inputs, dim3(2048), dim3(256), 0, stream,
                     (const f32x4*)x, (const f32x4*)h0,
                     (half4*)xh, (half4*)h16, (half4*)(h16 + B_ * D_));

  void* kargs[7] = {(void*)&WkT, (void*)&WrT, (void*)&xh, (void*)&c0,
                    (void*)&out, (void*)&h16, (void*)&bar};
  hipLaunchCooperativeKernel((void*)lstm_scan, dim3(256), dim3(256), kargs, 0, stream);
}